// Round 12
// baseline (503.471 us; speedup 1.0000x reference)
//
#include <hip/hip_runtime.h>
#include <hip/hip_bf16.h>

// Problem constants (B*T=8192 tokens, D=2048, E=8, I=1024, top-2)
constexpr int kN = 8192;
constexpr int kD = 2048;
constexpr int kE = 8;
constexpr int kI = 1024;

typedef __bf16 bf16x8 __attribute__((ext_vector_type(8)));
typedef float  f32x16 __attribute__((ext_vector_type(16)));

// ---- workspace layout (bytes). Total ~192.3 MiB ----
constexpr size_t OFF_COUNTS = 0;                            // 8 u32
constexpr size_t OFF_PSUM   = 64;                           // 8 f32
constexpr size_t OFF_OFFS   = 128;                          // 8 u32
constexpr size_t OFF_CURSOR = 192;                          // 8 u32
constexpr size_t OFF_TBASE  = 256;                          // 9 u32 padded tile starts
constexpr size_t OFF_TOPE   = 320;                          // N int2
constexpr size_t OFF_TOPW   = OFF_TOPE + (size_t)kN * 8;    // N float2
constexpr size_t OFF_SLOT   = OFF_TOPW + (size_t)kN * 8;    // N int2 (token -> its 2 slots)
constexpr size_t OFF_TOK    = OFF_SLOT + (size_t)kN * 8;    // 2N i32 (slot -> token)
constexpr size_t OFF_XG     = OFF_TOK + (size_t)kN * 8 + 64;        // 2N*D bf16 (64MiB) gathered acts
constexpr size_t OFF_W1B    = OFF_XG  + (size_t)2 * kN * kD * 2;    // E*I*D bf16 (32MiB)
constexpr size_t OFF_W3B    = OFF_W1B + (size_t)kE * kI * kD * 2;   // E*I*D bf16 (32MiB)
constexpr size_t OFF_W2B    = OFF_W3B + (size_t)kE * kI * kD * 2;   // E*D*I bf16 (32MiB)
constexpr size_t OFF_H      = OFF_W2B + (size_t)kE * kD * kI * 2;   // 2N*I bf16  (32MiB)
// O2 (2N*D bf16 = 64MiB) ALIASES Xg (dead after ffn_h)
constexpr size_t OFF_O2     = OFF_XG;

// async global->LDS, 16B per lane. LDS dest is wave-uniform base + lane*16.
typedef __attribute__((address_space(1))) const unsigned GU;
typedef __attribute__((address_space(3))) unsigned LU;
__device__ __forceinline__ void gload16(const void* g, void* l) {
    __builtin_amdgcn_global_load_lds((GU*)g, (LU*)l, 16, 0, 0);
}

// capacity-padded tiling: 136 >= 16384/128 + 8 partial tiles
constexpr int kMaxTiles = 136;
constexpr int kGemmGrid = kMaxTiles * 16;     // 2176, divisible by 8

// ------------------------------------------------------------------
// fp32 -> bf16 bulk convert for w1/w3/w2 PLUS the slot-gather of x,
// fused into ONE launch (4 segments x 2048 blocks).
//   seg 0..2: dense convert of w1/w3/w2 (n8seg vec8 each)
//   seg 3   : Xg[slot][:] = (bf16) x[tok[slot]][:]  (runs after scatter)
// ------------------------------------------------------------------
__global__ __launch_bounds__(256) void convert_gather_kernel(
    const float* __restrict__ s0, const float* __restrict__ s1,
    const float* __restrict__ s2, const float* __restrict__ x,
    const int* __restrict__ tok,
    __bf16* __restrict__ d0, __bf16* __restrict__ d1, __bf16* __restrict__ d2,
    __bf16* __restrict__ Xg, int n8seg)
{
    const int seg = blockIdx.x >> 11;       // 0..3
    const int bid = blockIdx.x & 2047;
    const int stride = 2048 * 256;
    if (seg < 3) {
        const float* src = (seg == 0) ? s0 : (seg == 1) ? s1 : s2;
        __bf16*      dst = (seg == 0) ? d0 : (seg == 1) ? d1 : d2;
        int i = bid * 256 + threadIdx.x;
        for (; i < n8seg; i += stride) {
            const float4* s = (const float4*)(src + (size_t)i * 8);
            float4 f0 = s[0], f1 = s[1];
            bf16x8 v;
            v[0]=(__bf16)f0.x; v[1]=(__bf16)f0.y; v[2]=(__bf16)f0.z; v[3]=(__bf16)f0.w;
            v[4]=(__bf16)f1.x; v[5]=(__bf16)f1.y; v[6]=(__bf16)f1.z; v[7]=(__bf16)f1.w;
            *(bf16x8*)(dst + (size_t)i * 8) = v;
        }
    } else {
        const int total = 2 * kN * (kD / 8);    // 4.2M vec8
        int i = bid * 256 + threadIdx.x;
        for (; i < total; i += stride) {
            const int slot = i >> 8;            // kD/8 = 256 vec8 per row
            const int d8   = (i & 255) * 8;
            const float4* s = (const float4*)(x + (size_t)tok[slot] * kD + d8);
            float4 f0 = s[0], f1 = s[1];
            bf16x8 v;
            v[0]=(__bf16)f0.x; v[1]=(__bf16)f0.y; v[2]=(__bf16)f0.z; v[3]=(__bf16)f0.w;
            v[4]=(__bf16)f1.x; v[5]=(__bf16)f1.y; v[6]=(__bf16)f1.z; v[7]=(__bf16)f1.w;
            *(bf16x8*)(Xg + (size_t)slot * kD + d8) = v;
        }
    }
}

// ------------------------------------------------------------------
// Gate: 4 waves/block, 1 token/wave. fp32 logits (float2 loads),
// softmax, top-2.
// ------------------------------------------------------------------
__global__ __launch_bounds__(256) void gate_kernel(
    const float* __restrict__ x, const float* __restrict__ gw,
    unsigned* __restrict__ counts, float* __restrict__ psum,
    int2* __restrict__ tope, float2* __restrict__ topw)
{
    const int tid  = threadIdx.x;
    const int lane = tid & 63;
    const int wv   = tid >> 6;
    const int t    = blockIdx.x * 4 + wv;

    const float2* xr = (const float2*)(x + (size_t)t * kD);
    float2 xv[16];
#pragma unroll
    for (int j = 0; j < 16; ++j) xv[j] = xr[lane + 64 * j];

    float s[8];
#pragma unroll
    for (int e = 0; e < 8; ++e) {
        const float2* gr = (const float2*)(gw + (size_t)e * kD);
        float a = 0.f;
#pragma unroll
        for (int j = 0; j < 16; ++j) {
            float2 g = gr[lane + 64 * j];
            a += xv[j].x * g.x + xv[j].y * g.y;
        }
        s[e] = a;
    }
#pragma unroll
    for (int off = 32; off > 0; off >>= 1) {
#pragma unroll
        for (int e = 0; e < 8; ++e) s[e] += __shfl_xor(s[e], off, 64);
    }
    float mx = s[0];
#pragma unroll
    for (int e = 1; e < 8; ++e) mx = fmaxf(mx, s[e]);
    float p[8]; float sum = 0.f;
#pragma unroll
    for (int e = 0; e < 8; ++e) { p[e] = expf(s[e] - mx); sum += p[e]; }
    float inv = 1.f / sum;
#pragma unroll
    for (int e = 0; e < 8; ++e) p[e] *= inv;

    // top-2 (strict '>' keeps lowest index on ties, matching lax.top_k)
    int e0 = 0; float p0 = p[0];
#pragma unroll
    for (int e = 1; e < 8; ++e) if (p[e] > p0) { p0 = p[e]; e0 = e; }
    int e1 = -1; float p1 = -1.f;
#pragma unroll
    for (int e = 0; e < 8; ++e) if (e != e0 && p[e] > p1) { p1 = p[e]; e1 = e; }
    float wn = 1.f / (p0 + p1);

    __shared__ float ps[4][8];
    __shared__ unsigned cnt[8];
    if (tid < 8) cnt[tid] = 0u;
    __syncthreads();
    if (lane == 0) {
#pragma unroll
        for (int e = 0; e < 8; ++e) ps[wv][e] = p[e];
        atomicAdd(&cnt[e0], 1u);
        atomicAdd(&cnt[e1], 1u);
        tope[t] = make_int2(e0, e1);
        topw[t] = make_float2(p0 * wn, p1 * wn);
    }
    __syncthreads();
    if (tid < 8) {
        atomicAdd(&psum[tid], ps[0][tid] + ps[1][tid] + ps[2][tid] + ps[3][tid]);
        if (cnt[tid]) atomicAdd(&counts[tid], cnt[tid]);
    }
}

// ------------------------------------------------------------------
// Scan: offsets/cursors/padded-tile-bases from counts; aux -> out[N*D]
// ------------------------------------------------------------------
__global__ void scan_kernel(const unsigned* __restrict__ counts,
                            const float* __restrict__ psum,
                            unsigned* __restrict__ offs,
                            unsigned* __restrict__ cursor,
                            unsigned* __restrict__ tbase,
                            float* __restrict__ out)
{
    if (threadIdx.x == 0) {
        unsigned off = 0, tb = 0;
        float a = 0.f;
        for (int e = 0; e < 8; ++e) {
            offs[e] = off; cursor[e] = off; off += counts[e];
            tbase[e] = tb; tb += (counts[e] + 127u) >> 7;
            a += ((float)counts[e] / (float)kN) * (psum[e] / (float)kN);
        }
        tbase[8] = tb;
        out[(size_t)kN * kD] = 0.01f * (float)kE * a;
    }
}

// ------------------------------------------------------------------
// Scatter: counting-sort token assignments by expert; record slot map
// ------------------------------------------------------------------
__global__ __launch_bounds__(256) void scatter_kernel(
    const int2* __restrict__ tope,
    unsigned* __restrict__ cursor, int* __restrict__ tok,
    int2* __restrict__ slotmap)
{
    int t = blockIdx.x * 256 + threadIdx.x;
    int2 ee = tope[t];
    unsigned q0 = atomicAdd(&cursor[ee.x], 1u);
    tok[q0] = t;
    unsigned q1 = atomicAdd(&cursor[ee.y], 1u);
    tok[q1] = t;
    slotmap[t] = make_int2((int)q0, (int)q1);
}

// XCD-chunked 1D decode: w -> (tile, ct). XCD(w)=w%8 (round-robin); the
// bijective chunk transform gives each XCD a contiguous orig range so the
// 16 ct-blocks sharing one A-panel land on ONE XCD's L2 concurrently.
__device__ __forceinline__ bool gemm_decode(
    const unsigned* __restrict__ tbase, int& e, int& mt, int& ct)
{
    const unsigned w = blockIdx.x;                     // 0..2175
    const unsigned orig = (w & 7u) * (kGemmGrid / 8) + (w >> 3);
    const int tile = (int)(orig >> 4);
    ct = (int)(orig & 15u);
    if ((unsigned)tile >= tbase[8]) return false;
    e = 0;
#pragma unroll
    for (int k = 1; k < 8; ++k) if (tbase[k] <= (unsigned)tile) e = k;
    mt = tile - (int)tbase[e];
    return true;
}

// ------------------------------------------------------------------
// C1 (R9 core, verbatim): 128x128 tile, BK=64, 4 waves 2x2, 64x64/wave
// = 2x2 frags of 32x32 (mfma_f32_32x32x16_bf16). A = Xg slot rows
// (linear -- required for the XCD-chunk L2 win, R11 lesson).
// B rows ordered [w1 h0-31 | w3 h0-31 | w1 h32-63 | w3 h32-63] so
// a1=acc[m][0], a3=acc[m][1] pair in-lane. C/D: col=lane&31,
// row=(reg&3)+8*(reg>>2)+4*(lane>>5)  [m74/m101].
// LDS XOR-swizzle: 16B slot p of row r holds logical p^(r&7);
// global source pre-swizzled (rule #21), reads apply same XOR.
// ------------------------------------------------------------------
__global__ __launch_bounds__(256) void ffn_h_kernel(
    const __bf16* __restrict__ Xg,
    const __bf16* __restrict__ w1b, const __bf16* __restrict__ w3b,
    const unsigned* __restrict__ counts, const unsigned* __restrict__ offs,
    const unsigned* __restrict__ tbase, __bf16* __restrict__ H)
{
    int e, mt, ct;
    if (!gemm_decode(tbase, e, mt, ct)) return;
    const unsigned n_e = counts[e];
    const unsigned base = offs[e];

    __shared__ __bf16 As[128][64];
    __shared__ __bf16 Bs[128][64];

    const int tid  = threadIdx.x;
    const int lane = tid & 63;
    const int wv   = tid >> 6;
    const int wr   = wv >> 1, wc = wv & 1;

    const __bf16* aptr[4];
    const __bf16* bptr[4];
    __bf16* alds[4];
    __bf16* blds[4];
#pragma unroll
    for (int j = 0; j < 4; ++j) {
        const int r = wv * 32 + j * 8 + (lane >> 3);
        const int c = (((lane & 7) ^ (r & 7)) << 3);   // pre-swizzled source col
        unsigned grow = (unsigned)(mt * 128 + r);
        grow = grow < n_e ? grow : (n_e - 1);
        aptr[j] = Xg + (size_t)(base + grow) * kD + c;
        alds[j] = &As[wv * 32 + j * 8][0];
        const int rr = r & 63;
        const int h  = ct * 64 + ((r >> 6) << 5) + (rr & 31);
        const __bf16* wsrc = (rr < 32) ? w1b : w3b;
        bptr[j] = wsrc + ((size_t)e * kI + h) * kD + c;
        blds[j] = &Bs[wv * 32 + j * 8][0];
    }

    f32x16 acc[2][2] = {};

    const int ar0 = wr * 64 + (lane & 31);
    const int ar1 = ar0 + 32;
    const int br0 = wc * 64 + (lane & 31);
    const int br1 = br0 + 32;
    const int sgl = lane >> 5;                 // k-group (0/1)

    for (int k0 = 0; k0 < kD; k0 += 64) {
#pragma unroll
        for (int j = 0; j < 4; ++j) {
            gload16(aptr[j], alds[j]);
            gload16(bptr[j], blds[j]);
            aptr[j] += 64; bptr[j] += 64;
        }
        __syncthreads();

#pragma unroll
        for (int kk = 0; kk < 4; ++kk) {
            const int s = kk * 2 + sgl;        // logical 16B slot (k = kk*16+sgl*8)
            bf16x8 a0 = *(const bf16x8*)&As[ar0][((s ^ (ar0 & 7)) << 3)];
            bf16x8 a1 = *(const bf16x8*)&As[ar1][((s ^ (ar1 & 7)) << 3)];
            bf16x8 b0 = *(const bf16x8*)&Bs[br0][((s ^ (br0 & 7)) << 3)];
            bf16x8 b1 = *(const bf16x8*)&Bs[br1][((s ^ (br1 & 7)) << 3)];
            acc[0][0] = __builtin_amdgcn_mfma_f32_32x32x16_bf16(a0, b0, acc[0][0], 0, 0, 0);
            acc[0][1] = __builtin_amdgcn_mfma_f32_32x32x16_bf16(a0, b1, acc[0][1], 0, 0, 0);
            acc[1][0] = __builtin_amdgcn_mfma_f32_32x32x16_bf16(a1, b0, acc[1][0], 0, 0, 0);
            acc[1][1] = __builtin_amdgcn_mfma_f32_32x32x16_bf16(a1, b1, acc[1][1], 0, 0, 0);
        }
        __syncthreads();
    }

    // epilogue: h = silu(a1)*a3
    const int c0    = lane & 31;
    const int rbase = 4 * (lane >> 5);
    const size_t hcol = (size_t)(ct * 64 + wc * 32 + c0);
#pragma unroll
    for (int m = 0; m < 2; ++m) {
#pragma unroll
        for (int reg = 0; reg < 16; ++reg) {
            const int crow = (reg & 3) + 8 * (reg >> 2) + rbase;
            const unsigned grow = (unsigned)(mt * 128 + wr * 64 + m * 32 + crow);
            if (grow < n_e) {
                float a1 = acc[m][0][reg];
                float a3 = acc[m][1][reg];
                float h = a1 / (1.f + __expf(-a1)) * a3;
                H[(size_t)(base + grow) * kI + hcol] = (__bf16)h;
            }
        }
    }
}

// ------------------------------------------------------------------
// C2 (R9 core, verbatim): 128 slots x 128 d-cols, BK=64, K=1024.
// Writes O2[slot][d] bf16 -- no atomics; combine pass gathers per token.
// ------------------------------------------------------------------
__global__ __launch_bounds__(256) void ffn_out_kernel(
    const __bf16* __restrict__ H, const __bf16* __restrict__ w2b,
    const unsigned* __restrict__ counts, const unsigned* __restrict__ offs,
    const unsigned* __restrict__ tbase, __bf16* __restrict__ O2)
{
    int e, mt, ct;
    if (!gemm_decode(tbase, e, mt, ct)) return;
    const unsigned n_e = counts[e];
    const unsigned base = offs[e];

    __shared__ __bf16 As[128][64];
    __shared__ __bf16 Bs[128][64];

    const int tid  = threadIdx.x;
    const int lane = tid & 63;
    const int wv   = tid >> 6;
    const int wr   = wv >> 1, wc = wv & 1;

    const __bf16* aptr[4];
    const __bf16* bptr[4];
    __bf16* alds[4];
    __bf16* blds[4];
#pragma unroll
    for (int j = 0; j < 4; ++j) {
        const int r = wv * 32 + j * 8 + (lane >> 3);
        const int c = (((lane & 7) ^ (r & 7)) << 3);
        unsigned grow = (unsigned)(mt * 128 + r);
        grow = grow < n_e ? grow : (n_e - 1);
        aptr[j] = H + (size_t)(base + grow) * kI + c;
        alds[j] = &As[wv * 32 + j * 8][0];
        bptr[j] = w2b + ((size_t)e * kD + ct * 128 + r) * kI + c;
        blds[j] = &Bs[wv * 32 + j * 8][0];
    }

    f32x16 acc[2][2] = {};

    const int ar0 = wr * 64 + (lane & 31);
    const int ar1 = ar0 + 32;
    const int br0 = wc * 64 + (lane & 31);
    const int br1 = br0 + 32;
    const int sgl = lane >> 5;

    for (int k0 = 0; k0 < kI; k0 += 64) {
#pragma unroll
        for (int j = 0; j < 4; ++j) {
            gload16(aptr[j], alds[j]);
            gload16(bptr[j], blds[j]);
            aptr[j] += 64; bptr[j] += 64;
        }
        __syncthreads();

#pragma unroll
        for (int kk = 0; kk < 4; ++kk) {
            const int s = kk * 2 + sgl;
            bf16x8 a0 = *(const bf16x8*)&As[ar0][((s ^ (ar0 & 7)) << 3)];
            bf16x8 a1 = *(const bf16x8*)&As[ar1][((s ^ (ar1 & 7)) << 3)];
            bf16x8 b0 = *(const bf16x8*)&Bs[br0][((s ^ (br0 & 7)) << 3)];
            bf16x8 b1 = *(const bf16x8*)&Bs[br1][((s ^ (br1 & 7)) << 3)];
            acc[0][0] = __builtin_amdgcn_mfma_f32_32x32x16_bf16(a0, b0, acc[0][0], 0, 0, 0);
            acc[0][1] = __builtin_amdgcn_mfma_f32_32x32x16_bf16(a0, b1, acc[0][1], 0, 0, 0);
            acc[1][0] = __builtin_amdgcn_mfma_f32_32x32x16_bf16(a1, b0, acc[1][0], 0, 0, 0);
            acc[1][1] = __builtin_amdgcn_mfma_f32_32x32x16_bf16(a1, b1, acc[1][1], 0, 0, 0);
        }
        __syncthreads();
    }

    const int c0    = lane & 31;
    const int rbase = 4 * (lane >> 5);
#pragma unroll
    for (int m = 0; m < 2; ++m) {
#pragma unroll
        for (int reg = 0; reg < 16; ++reg) {
            const int crow = (reg & 3) + 8 * (reg >> 2) + rbase;
            const unsigned grow = (unsigned)(mt * 128 + wr * 64 + m * 32 + crow);
            if (grow < n_e) {
                __bf16* orow = O2 + (size_t)(base + grow) * kD + ct * 128 + wc * 64 + c0;
                orow[0]  = (__bf16)acc[m][0][reg];
                orow[32] = (__bf16)acc[m][1][reg];
            }
        }
    }
}

// ------------------------------------------------------------------
// Combine: out[t] = w0 * O2[slot0[t]] + w1 * O2[slot1[t]]  (fp32 out)
// ------------------------------------------------------------------
__global__ __launch_bounds__(256) void combine_kernel(
    const __bf16* __restrict__ O2, const int2* __restrict__ slotmap,
    const float2* __restrict__ topw, float* __restrict__ out)
{
    const int total = kN * (kD / 8);             // 2.1M vec8
    int i = blockIdx.x * 256 + threadIdx.x;
    const int stride = gridDim.x * 256;
    for (; i < total; i += stride) {
        const int t  = i >> 8;                   // kD/8 = 256 vec8 per token
        const int d8 = (i & 255) * 8;
        const int2   sm = slotmap[t];
        const float2 w  = topw[t];
        bf16x8 a = *(const bf16x8*)(O2 + (size_t)sm.x * kD + d8);
        bf16x8 b = *(const bf16x8*)(O2 + (size_t)sm.y * kD + d8);
        float r[8];
#pragma unroll
        for (int j = 0; j < 8; ++j)
            r[j] = w.x * (float)a[j] + w.y * (float)b[j];
        float4* o = (float4*)(out + (size_t)i * 8);
        o[0] = make_float4(r[0], r[1], r[2], r[3]);
        o[1] = make_float4(r[4], r[5], r[6], r[7]);
    }
}

// ------------------------------------------------------------------
extern "C" void kernel_launch(void* const* d_in, const int* in_sizes, int n_in,
                              void* d_out, int out_size, void* d_ws, size_t ws_size,
                              hipStream_t stream)
{
    const float* x  = (const float*)d_in[0];
    const float* gw = (const float*)d_in[1];
    const float* w1 = (const float*)d_in[2];
    const float* w3 = (const float*)d_in[3];
    const float* w2 = (const float*)d_in[4];
    float* out = (float*)d_out;
    char*  ws  = (char*)d_ws;

    unsigned* counts = (unsigned*)(ws + OFF_COUNTS);
    float*    psum   = (float*)(ws + OFF_PSUM);
    unsigned* offs   = (unsigned*)(ws + OFF_OFFS);
    unsigned* cursor = (unsigned*)(ws + OFF_CURSOR);
    unsigned* tbase  = (unsigned*)(ws + OFF_TBASE);
    int2*     tope   = (int2*)(ws + OFF_TOPE);
    float2*   topw   = (float2*)(ws + OFF_TOPW);
    int2*     slotmap= (int2*)(ws + OFF_SLOT);
    int*      tok    = (int*)(ws + OFF_TOK);
    __bf16*   Xg     = (__bf16*)(ws + OFF_XG);
    __bf16*   w1b    = (__bf16*)(ws + OFF_W1B);
    __bf16*   w3b    = (__bf16*)(ws + OFF_W3B);
    __bf16*   w2b    = (__bf16*)(ws + OFF_W2B);
    __bf16*   H      = (__bf16*)(ws + OFF_H);
    __bf16*   O2     = (__bf16*)(ws + OFF_O2);   // aliases Xg (dead after ffn_h)

    hipMemsetAsync(d_ws, 0, 320, stream);        // counts/psum/offs/cursor/tbase

    gate_kernel<<<kN / 4, 256, 0, stream>>>(x, gw, counts, psum, tope, topw);
    scan_kernel<<<1, 64, 0, stream>>>(counts, psum, offs, cursor, tbase, out);
    scatter_kernel<<<kN / 256, 256, 0, stream>>>(tope, cursor, tok, slotmap);

    convert_gather_kernel<<<4 * 2048, 256, 0, stream>>>(
        w1, w3, w2, x, tok, w1b, w3b, w2b, Xg, kE * kI * kD / 8);

    ffn_h_kernel<<<kGemmGrid, 256, 0, stream>>>(
        Xg, w1b, w3b, counts, offs, tbase, H);
    ffn_out_kernel<<<kGemmGrid, 256, 0, stream>>>(
        H, w2b, counts, offs, tbase, O2);
    combine_kernel<<<2048, 256, 0, stream>>>(O2, slotmap, topw, out);
}

// Round 13
// 459.755 us; speedup vs baseline: 1.0951x; 1.0951x over previous
//
#include <hip/hip_runtime.h>
#include <hip/hip_bf16.h>

// Problem constants (B*T=8192 tokens, D=2048, E=8, I=1024, top-2)
constexpr int kN = 8192;
constexpr int kD = 2048;
constexpr int kE = 8;
constexpr int kI = 1024;

typedef __bf16 bf16x8 __attribute__((ext_vector_type(8)));
typedef float  f32x16 __attribute__((ext_vector_type(16)));

// ---- workspace layout (bytes). Total ~192.3 MiB ----
constexpr size_t OFF_COUNTS = 0;                            // 8 u32
constexpr size_t OFF_PSUM   = 64;                           // 8 f32
constexpr size_t OFF_OFFS   = 128;                          // 8 u32
constexpr size_t OFF_CURSOR = 192;                          // 8 u32
constexpr size_t OFF_TBASE  = 256;                          // 9 u32 padded tile starts
constexpr size_t OFF_TOPE   = 320;                          // N int2
constexpr size_t OFF_TOPW   = OFF_TOPE + (size_t)kN * 8;    // N float2
constexpr size_t OFF_SLOT   = OFF_TOPW + (size_t)kN * 8;    // N int2 (token -> its 2 slots)
constexpr size_t OFF_TOK    = OFF_SLOT + (size_t)kN * 8;    // 2N i32 (slot -> token)
constexpr size_t OFF_XG     = OFF_TOK + (size_t)kN * 8 + 64;        // 2N*D bf16 (64MiB) gathered acts
constexpr size_t OFF_W1B    = OFF_XG  + (size_t)2 * kN * kD * 2;    // E*I*D bf16 (32MiB)
constexpr size_t OFF_W3B    = OFF_W1B + (size_t)kE * kI * kD * 2;   // E*I*D bf16 (32MiB)
constexpr size_t OFF_W2B    = OFF_W3B + (size_t)kE * kI * kD * 2;   // E*D*I bf16 (32MiB)
constexpr size_t OFF_H      = OFF_W2B + (size_t)kE * kD * kI * 2;   // 2N*I bf16  (32MiB)
// O2 (2N*D bf16 = 64MiB) ALIASES Xg (dead after ffn_h)
constexpr size_t OFF_O2     = OFF_XG;

// async global->LDS, 16B per lane. LDS dest is wave-uniform base + lane*16.
typedef __attribute__((address_space(1))) const unsigned GU;
typedef __attribute__((address_space(3))) unsigned LU;
__device__ __forceinline__ void gload16(const void* g, void* l) {
    __builtin_amdgcn_global_load_lds((GU*)g, (LU*)l, 16, 0, 0);
}

// capacity-padded tiling: 136 >= 16384/128 + 8 partial tiles
constexpr int kMaxTiles = 136;
constexpr int kGemmGrid = kMaxTiles * 16;     // 2176, divisible by 8

// ------------------------------------------------------------------
// fp32 -> bf16 bulk convert for w1, w3, w2 in ONE launch.
// ------------------------------------------------------------------
__global__ __launch_bounds__(256) void convert3_kernel(
    const float* __restrict__ s0, const float* __restrict__ s1,
    const float* __restrict__ s2,
    __bf16* __restrict__ d0, __bf16* __restrict__ d1, __bf16* __restrict__ d2,
    int n8seg)
{
    const int seg = blockIdx.x >> 11;       // 0,1,2
    const int bid = blockIdx.x & 2047;
    const float* src = (seg == 0) ? s0 : (seg == 1) ? s1 : s2;
    __bf16*      dst = (seg == 0) ? d0 : (seg == 1) ? d1 : d2;
    int i = bid * 256 + threadIdx.x;
    const int stride = 2048 * 256;
    for (; i < n8seg; i += stride) {
        const float4* s = (const float4*)(src + (size_t)i * 8);
        float4 f0 = s[0], f1 = s[1];
        bf16x8 v;
        v[0]=(__bf16)f0.x; v[1]=(__bf16)f0.y; v[2]=(__bf16)f0.z; v[3]=(__bf16)f0.w;
        v[4]=(__bf16)f1.x; v[5]=(__bf16)f1.y; v[6]=(__bf16)f1.z; v[7]=(__bf16)f1.w;
        *(bf16x8*)(dst + (size_t)i * 8) = v;
    }
}

// ------------------------------------------------------------------
// Gate: 4 waves/block, 1 token/wave. fp32 logits, softmax, top-2.
// ------------------------------------------------------------------
__global__ __launch_bounds__(256) void gate_kernel(
    const float* __restrict__ x, const float* __restrict__ gw,
    unsigned* __restrict__ counts, float* __restrict__ psum,
    int2* __restrict__ tope, float2* __restrict__ topw)
{
    const int tid  = threadIdx.x;
    const int lane = tid & 63;
    const int wv   = tid >> 6;
    const int t    = blockIdx.x * 4 + wv;

    const float* xr = x + (size_t)t * kD;
    float xv[32];
#pragma unroll
    for (int j = 0; j < 32; ++j) xv[j] = xr[lane + 64 * j];

    float s[8];
#pragma unroll
    for (int e = 0; e < 8; ++e) {
        const float* gr = gw + (size_t)e * kD;
        float a = 0.f;
#pragma unroll
        for (int j = 0; j < 32; ++j) a += xv[j] * gr[lane + 64 * j];
        s[e] = a;
    }
#pragma unroll
    for (int off = 32; off > 0; off >>= 1) {
#pragma unroll
        for (int e = 0; e < 8; ++e) s[e] += __shfl_xor(s[e], off, 64);
    }
    float mx = s[0];
#pragma unroll
    for (int e = 1; e < 8; ++e) mx = fmaxf(mx, s[e]);
    float p[8]; float sum = 0.f;
#pragma unroll
    for (int e = 0; e < 8; ++e) { p[e] = expf(s[e] - mx); sum += p[e]; }
    float inv = 1.f / sum;
#pragma unroll
    for (int e = 0; e < 8; ++e) p[e] *= inv;

    // top-2 (strict '>' keeps lowest index on ties, matching lax.top_k)
    int e0 = 0; float p0 = p[0];
#pragma unroll
    for (int e = 1; e < 8; ++e) if (p[e] > p0) { p0 = p[e]; e0 = e; }
    int e1 = -1; float p1 = -1.f;
#pragma unroll
    for (int e = 0; e < 8; ++e) if (e != e0 && p[e] > p1) { p1 = p[e]; e1 = e; }
    float wn = 1.f / (p0 + p1);

    __shared__ float ps[4][8];
    __shared__ unsigned cnt[8];
    if (tid < 8) cnt[tid] = 0u;
    __syncthreads();
    if (lane == 0) {
#pragma unroll
        for (int e = 0; e < 8; ++e) ps[wv][e] = p[e];
        atomicAdd(&cnt[e0], 1u);
        atomicAdd(&cnt[e1], 1u);
        tope[t] = make_int2(e0, e1);
        topw[t] = make_float2(p0 * wn, p1 * wn);
    }
    __syncthreads();
    if (tid < 8) {
        atomicAdd(&psum[tid], ps[0][tid] + ps[1][tid] + ps[2][tid] + ps[3][tid]);
        if (cnt[tid]) atomicAdd(&counts[tid], cnt[tid]);
    }
}

// ------------------------------------------------------------------
// Scan: offsets/cursors/padded-tile-bases from counts; aux -> out[N*D]
// ------------------------------------------------------------------
__global__ void scan_kernel(const unsigned* __restrict__ counts,
                            const float* __restrict__ psum,
                            unsigned* __restrict__ offs,
                            unsigned* __restrict__ cursor,
                            unsigned* __restrict__ tbase,
                            float* __restrict__ out)
{
    if (threadIdx.x == 0) {
        unsigned off = 0, tb = 0;
        float a = 0.f;
        for (int e = 0; e < 8; ++e) {
            offs[e] = off; cursor[e] = off; off += counts[e];
            tbase[e] = tb; tb += (counts[e] + 127u) >> 7;
            a += ((float)counts[e] / (float)kN) * (psum[e] / (float)kN);
        }
        tbase[8] = tb;
        out[(size_t)kN * kD] = 0.01f * (float)kE * a;
    }
}

// ------------------------------------------------------------------
// Scatter: counting-sort token assignments by expert; record slot map
// ------------------------------------------------------------------
__global__ __launch_bounds__(256) void scatter_kernel(
    const int2* __restrict__ tope,
    unsigned* __restrict__ cursor, int* __restrict__ tok,
    int2* __restrict__ slotmap)
{
    int t = blockIdx.x * 256 + threadIdx.x;
    int2 ee = tope[t];
    unsigned q0 = atomicAdd(&cursor[ee.x], 1u);
    tok[q0] = t;
    unsigned q1 = atomicAdd(&cursor[ee.y], 1u);
    tok[q1] = t;
    slotmap[t] = make_int2((int)q0, (int)q1);
}

// ------------------------------------------------------------------
// Gather: Xg[slot][:] = (bf16) x[tok[slot]][:]
// ------------------------------------------------------------------
__global__ __launch_bounds__(256) void gather_kernel(
    const float* __restrict__ x, const int* __restrict__ tok,
    __bf16* __restrict__ Xg)
{
    const int total = 2 * kN * (kD / 8);        // 4.2M vec8
    int i = blockIdx.x * 256 + threadIdx.x;
    const int stride = gridDim.x * 256;
    for (; i < total; i += stride) {
        const int slot = i >> 8;                // kD/8 = 256 vec8 per row
        const int d8   = (i & 255) * 8;
        const float4* s = (const float4*)(x + (size_t)tok[slot] * kD + d8);
        float4 f0 = s[0], f1 = s[1];
        bf16x8 v;
        v[0]=(__bf16)f0.x; v[1]=(__bf16)f0.y; v[2]=(__bf16)f0.z; v[3]=(__bf16)f0.w;
        v[4]=(__bf16)f1.x; v[5]=(__bf16)f1.y; v[6]=(__bf16)f1.z; v[7]=(__bf16)f1.w;
        *(bf16x8*)(Xg + (size_t)slot * kD + d8) = v;
    }
}

// XCD-chunked 1D decode: w -> (tile, ct). XCD(w)=w%8 (round-robin); the
// bijective chunk transform gives each XCD a contiguous orig range so the
// 16 ct-blocks sharing one A-panel land on ONE XCD's L2 concurrently.
__device__ __forceinline__ bool gemm_decode(
    const unsigned* __restrict__ tbase, int& e, int& mt, int& ct)
{
    const unsigned w = blockIdx.x;                     // 0..2175
    const unsigned orig = (w & 7u) * (kGemmGrid / 8) + (w >> 3);
    const int tile = (int)(orig >> 4);
    ct = (int)(orig & 15u);
    if ((unsigned)tile >= tbase[8]) return false;
    e = 0;
#pragma unroll
    for (int k = 1; k < 8; ++k) if (tbase[k] <= (unsigned)tile) e = k;
    mt = tile - (int)tbase[e];
    return true;
}

// ------------------------------------------------------------------
// C1 (R9 core): 128x128 tile, BK=64, 4 waves 2x2, 64x64/wave = 2x2
// frags of 32x32 (mfma_f32_32x32x16_bf16). A = Xg slot rows (linear).
// B rows ordered [w1 h0-31 | w3 h0-31 | w1 h32-63 | w3 h32-63] so
// a1=acc[m][0], a3=acc[m][1] pair in-lane. C/D: col=lane&31,
// row=(reg&3)+8*(reg>>2)+4*(lane>>5)  [m74/m101].
// LDS XOR-swizzle: 16B slot p of row r holds logical p^(r&7);
// global source pre-swizzled (rule #21), reads apply same XOR.
// ------------------------------------------------------------------
__global__ __launch_bounds__(256) void ffn_h_kernel(
    const __bf16* __restrict__ Xg,
    const __bf16* __restrict__ w1b, const __bf16* __restrict__ w3b,
    const unsigned* __restrict__ counts, const unsigned* __restrict__ offs,
    const unsigned* __restrict__ tbase, __bf16* __restrict__ H)
{
    int e, mt, ct;
    if (!gemm_decode(tbase, e, mt, ct)) return;
    const unsigned n_e = counts[e];
    const unsigned base = offs[e];

    __shared__ __bf16 As[128][64];
    __shared__ __bf16 Bs[128][64];

    const int tid  = threadIdx.x;
    const int lane = tid & 63;
    const int wv   = tid >> 6;
    const int wr   = wv >> 1, wc = wv & 1;

    const __bf16* aptr[4];
    const __bf16* bptr[4];
    __bf16* alds[4];
    __bf16* blds[4];
#pragma unroll
    for (int j = 0; j < 4; ++j) {
        const int r = wv * 32 + j * 8 + (lane >> 3);
        const int c = (((lane & 7) ^ (r & 7)) << 3);   // pre-swizzled source col
        unsigned grow = (unsigned)(mt * 128 + r);
        grow = grow < n_e ? grow : (n_e - 1);
        aptr[j] = Xg + (size_t)(base + grow) * kD + c;
        alds[j] = &As[wv * 32 + j * 8][0];
        const int rr = r & 63;
        const int h  = ct * 64 + ((r >> 6) << 5) + (rr & 31);
        const __bf16* wsrc = (rr < 32) ? w1b : w3b;
        bptr[j] = wsrc + ((size_t)e * kI + h) * kD + c;
        blds[j] = &Bs[wv * 32 + j * 8][0];
    }

    f32x16 acc[2][2] = {};

    const int ar0 = wr * 64 + (lane & 31);
    const int ar1 = ar0 + 32;
    const int br0 = wc * 64 + (lane & 31);
    const int br1 = br0 + 32;
    const int sgl = lane >> 5;                 // k-group (0/1)

    for (int k0 = 0; k0 < kD; k0 += 64) {
#pragma unroll
        for (int j = 0; j < 4; ++j) {
            gload16(aptr[j], alds[j]);
            gload16(bptr[j], blds[j]);
            aptr[j] += 64; bptr[j] += 64;
        }
        __syncthreads();

#pragma unroll
        for (int kk = 0; kk < 4; ++kk) {
            const int s = kk * 2 + sgl;        // logical 16B slot (k = kk*16+sgl*8)
            bf16x8 a0 = *(const bf16x8*)&As[ar0][((s ^ (ar0 & 7)) << 3)];
            bf16x8 a1 = *(const bf16x8*)&As[ar1][((s ^ (ar1 & 7)) << 3)];
            bf16x8 b0 = *(const bf16x8*)&Bs[br0][((s ^ (br0 & 7)) << 3)];
            bf16x8 b1 = *(const bf16x8*)&Bs[br1][((s ^ (br1 & 7)) << 3)];
            acc[0][0] = __builtin_amdgcn_mfma_f32_32x32x16_bf16(a0, b0, acc[0][0], 0, 0, 0);
            acc[0][1] = __builtin_amdgcn_mfma_f32_32x32x16_bf16(a0, b1, acc[0][1], 0, 0, 0);
            acc[1][0] = __builtin_amdgcn_mfma_f32_32x32x16_bf16(a1, b0, acc[1][0], 0, 0, 0);
            acc[1][1] = __builtin_amdgcn_mfma_f32_32x32x16_bf16(a1, b1, acc[1][1], 0, 0, 0);
        }
        __syncthreads();
    }

    // epilogue: h = silu(a1)*a3
    const int c0    = lane & 31;
    const int rbase = 4 * (lane >> 5);
    const size_t hcol = (size_t)(ct * 64 + wc * 32 + c0);
#pragma unroll
    for (int m = 0; m < 2; ++m) {
#pragma unroll
        for (int reg = 0; reg < 16; ++reg) {
            const int crow = (reg & 3) + 8 * (reg >> 2) + rbase;
            const unsigned grow = (unsigned)(mt * 128 + wr * 64 + m * 32 + crow);
            if (grow < n_e) {
                float a1 = acc[m][0][reg];
                float a3 = acc[m][1][reg];
                float h = a1 / (1.f + __expf(-a1)) * a3;
                H[(size_t)(base + grow) * kI + hcol] = (__bf16)h;
            }
        }
    }
}

// ------------------------------------------------------------------
// C2 (R9 core): 128 slots x 128 d-cols, BK=64, K=1024, 32x32x16 MFMA.
// Writes O2[slot][d] bf16 -- no atomics; combine pass gathers per token.
// ------------------------------------------------------------------
__global__ __launch_bounds__(256) void ffn_out_kernel(
    const __bf16* __restrict__ H, const __bf16* __restrict__ w2b,
    const unsigned* __restrict__ counts, const unsigned* __restrict__ offs,
    const unsigned* __restrict__ tbase, __bf16* __restrict__ O2)
{
    int e, mt, ct;
    if (!gemm_decode(tbase, e, mt, ct)) return;
    const unsigned n_e = counts[e];
    const unsigned base = offs[e];

    __shared__ __bf16 As[128][64];
    __shared__ __bf16 Bs[128][64];

    const int tid  = threadIdx.x;
    const int lane = tid & 63;
    const int wv   = tid >> 6;
    const int wr   = wv >> 1, wc = wv & 1;

    const __bf16* aptr[4];
    const __bf16* bptr[4];
    __bf16* alds[4];
    __bf16* blds[4];
#pragma unroll
    for (int j = 0; j < 4; ++j) {
        const int r = wv * 32 + j * 8 + (lane >> 3);
        const int c = (((lane & 7) ^ (r & 7)) << 3);
        unsigned grow = (unsigned)(mt * 128 + r);
        grow = grow < n_e ? grow : (n_e - 1);
        aptr[j] = H + (size_t)(base + grow) * kI + c;
        alds[j] = &As[wv * 32 + j * 8][0];
        bptr[j] = w2b + ((size_t)e * kD + ct * 128 + r) * kI + c;
        blds[j] = &Bs[wv * 32 + j * 8][0];
    }

    f32x16 acc[2][2] = {};

    const int ar0 = wr * 64 + (lane & 31);
    const int ar1 = ar0 + 32;
    const int br0 = wc * 64 + (lane & 31);
    const int br1 = br0 + 32;
    const int sgl = lane >> 5;

    for (int k0 = 0; k0 < kI; k0 += 64) {
#pragma unroll
        for (int j = 0; j < 4; ++j) {
            gload16(aptr[j], alds[j]);
            gload16(bptr[j], blds[j]);
            aptr[j] += 64; bptr[j] += 64;
        }
        __syncthreads();

#pragma unroll
        for (int kk = 0; kk < 4; ++kk) {
            const int s = kk * 2 + sgl;
            bf16x8 a0 = *(const bf16x8*)&As[ar0][((s ^ (ar0 & 7)) << 3)];
            bf16x8 a1 = *(const bf16x8*)&As[ar1][((s ^ (ar1 & 7)) << 3)];
            bf16x8 b0 = *(const bf16x8*)&Bs[br0][((s ^ (br0 & 7)) << 3)];
            bf16x8 b1 = *(const bf16x8*)&Bs[br1][((s ^ (br1 & 7)) << 3)];
            acc[0][0] = __builtin_amdgcn_mfma_f32_32x32x16_bf16(a0, b0, acc[0][0], 0, 0, 0);
            acc[0][1] = __builtin_amdgcn_mfma_f32_32x32x16_bf16(a0, b1, acc[0][1], 0, 0, 0);
            acc[1][0] = __builtin_amdgcn_mfma_f32_32x32x16_bf16(a1, b0, acc[1][0], 0, 0, 0);
            acc[1][1] = __builtin_amdgcn_mfma_f32_32x32x16_bf16(a1, b1, acc[1][1], 0, 0, 0);
        }
        __syncthreads();
    }

    const int c0    = lane & 31;
    const int rbase = 4 * (lane >> 5);
#pragma unroll
    for (int m = 0; m < 2; ++m) {
#pragma unroll
        for (int reg = 0; reg < 16; ++reg) {
            const int crow = (reg & 3) + 8 * (reg >> 2) + rbase;
            const unsigned grow = (unsigned)(mt * 128 + wr * 64 + m * 32 + crow);
            if (grow < n_e) {
                __bf16* orow = O2 + (size_t)(base + grow) * kD + ct * 128 + wc * 64 + c0;
                orow[0]  = (__bf16)acc[m][0][reg];
                orow[32] = (__bf16)acc[m][1][reg];
            }
        }
    }
}

// ------------------------------------------------------------------
// Combine: out[t] = w0 * O2[slot0[t]] + w1 * O2[slot1[t]]  (fp32 out)
// ------------------------------------------------------------------
__global__ __launch_bounds__(256) void combine_kernel(
    const __bf16* __restrict__ O2, const int2* __restrict__ slotmap,
    const float2* __restrict__ topw, float* __restrict__ out)
{
    const int total = kN * (kD / 8);             // 2.1M vec8
    int i = blockIdx.x * 256 + threadIdx.x;
    const int stride = gridDim.x * 256;
    for (; i < total; i += stride) {
        const int t  = i >> 8;                   // kD/8 = 256 vec8 per token
        const int d8 = (i & 255) * 8;
        const int2   sm = slotmap[t];
        const float2 w  = topw[t];
        bf16x8 a = *(const bf16x8*)(O2 + (size_t)sm.x * kD + d8);
        bf16x8 b = *(const bf16x8*)(O2 + (size_t)sm.y * kD + d8);
        float r[8];
#pragma unroll
        for (int j = 0; j < 8; ++j)
            r[j] = w.x * (float)a[j] + w.y * (float)b[j];
        float4* o = (float4*)(out + (size_t)i * 8);
        o[0] = make_float4(r[0], r[1], r[2], r[3]);
        o[1] = make_float4(r[4], r[5], r[6], r[7]);
    }
}

// ------------------------------------------------------------------
extern "C" void kernel_launch(void* const* d_in, const int* in_sizes, int n_in,
                              void* d_out, int out_size, void* d_ws, size_t ws_size,
                              hipStream_t stream)
{
    const float* x  = (const float*)d_in[0];
    const float* gw = (const float*)d_in[1];
    const float* w1 = (const float*)d_in[2];
    const float* w3 = (const float*)d_in[3];
    const float* w2 = (const float*)d_in[4];
    float* out = (float*)d_out;
    char*  ws  = (char*)d_ws;

    unsigned* counts = (unsigned*)(ws + OFF_COUNTS);
    float*    psum   = (float*)(ws + OFF_PSUM);
    unsigned* offs   = (unsigned*)(ws + OFF_OFFS);
    unsigned* cursor = (unsigned*)(ws + OFF_CURSOR);
    unsigned* tbase  = (unsigned*)(ws + OFF_TBASE);
    int2*     tope   = (int2*)(ws + OFF_TOPE);
    float2*   topw   = (float2*)(ws + OFF_TOPW);
    int2*     slotmap= (int2*)(ws + OFF_SLOT);
    int*      tok    = (int*)(ws + OFF_TOK);
    __bf16*   Xg     = (__bf16*)(ws + OFF_XG);
    __bf16*   w1b    = (__bf16*)(ws + OFF_W1B);
    __bf16*   w3b    = (__bf16*)(ws + OFF_W3B);
    __bf16*   w2b    = (__bf16*)(ws + OFF_W2B);
    __bf16*   H      = (__bf16*)(ws + OFF_H);
    __bf16*   O2     = (__bf16*)(ws + OFF_O2);   // aliases Xg (dead after ffn_h)

    hipMemsetAsync(d_ws, 0, 320, stream);        // counts/psum/offs/cursor/tbase

    gate_kernel<<<kN / 4, 256, 0, stream>>>(x, gw, counts, psum, tope, topw);
    scan_kernel<<<1, 64, 0, stream>>>(counts, psum, offs, cursor, tbase, out);
    scatter_kernel<<<kN / 256, 256, 0, stream>>>(tope, cursor, tok, slotmap);

    convert3_kernel<<<3 * 2048, 256, 0, stream>>>(
        w1, w3, w2, w1b, w3b, w2b, kE * kI * kD / 8);
    gather_kernel<<<2048, 256, 0, stream>>>(x, tok, Xg);

    ffn_h_kernel<<<kGemmGrid, 256, 0, stream>>>(
        Xg, w1b, w3b, counts, offs, tbase, H);
    ffn_out_kernel<<<kGemmGrid, 256, 0, stream>>>(
        H, w2b, counts, offs, tbase, O2);
    combine_kernel<<<2048, 256, 0, stream>>>(O2, slotmap, topw, out);
}